// Round 12
// baseline (236.690 us; speedup 1.0000x reference)
//
#include <hip/hip_runtime.h>
#include <math.h>

// MoE gate: logits = x[16384,2048] @ W^T[2048,64]; top-8; softmax over top-8.
//
// Round-14: proven async-LDS staging (rounds 4-7 machinery: global_load_lds +
// inline-asm counted vmcnt + explicit barriers — the one schedule hipcc never
// collapsed) feeding the proven bf16x3 MFMA core (rounds 9-12). Round-13
// showed register-only pipelines get collapsed by the scheduler (VGPR 56 <
// the ~104 the pipeline needs); asm barriers make the pipeline durable.
//
// Geometry: grid 512, block 512 thr = 8 waves = (m in 2) x (n4 in 4); TOK=32.
//   Wave = 16 tok x 16 exp x FULL 2048 k -> no k-split, no part-reduce,
//   acc = one f32x4. 32 iterations x 64 k.
//   B: all 8 waves share one 24 KB chunk/iter (frags (ksg in 2i..2i+1, nt,
//   sp)), contiguous in ws; staged double-buffered by global_load_lds (wave w
//   stages chunks 3w..3w+2); sched_barrier(0) pins issue order [stage, x] so
//   the counted vmcnt(4) provably retires the stage; ONE s_barrier per iter.
//   x: global->reg depth-2 prefetch (4 float4/iter); the barrier fences stop
//   the scheduler from sinking these loads (round-13's failure mode).
//   LDS: B dbuf 48 KB + logits[64][32] 8 KB = 56 KB -> 2 blocks/CU;
//   VGPR ~105 <= 128 ((512,2) cap). ds_read_b128 lane-linear: conflict-free.
// Numerics/prologue/top-8: verbatim from rounds 9-12 (twice-verified).
// C/D layout (m89-verified): col(=expert)=lane&15, row(=token)=(lane>>4)*4+reg.

#define H_DIM 2048
#define N_EXP 64
#define TOPK 8
#define TOK 32
#define NIT 32  // iterations of 64 k

typedef __attribute__((ext_vector_type(8))) short bf16x8;
typedef __attribute__((ext_vector_type(4))) float f32x4;

union FragU { uint4 q; unsigned u[4]; bf16x8 s; };

__device__ inline unsigned cvt_pk_bf16(float lo, float hi) {
  unsigned d;
  asm("v_cvt_pk_bf16_f32 %0, %1, %2" : "=v"(d) : "v"(lo), "v"(hi));
  return d;
}

// split 8 f32 (one A/B fragment worth) into 3 packed-bf16 fragments
__device__ inline void split3(const float* e, unsigned* dh, unsigned* dm,
                              unsigned* dl) {
#pragma unroll
  for (int p = 0; p < 4; ++p) {
    const float f0 = e[2 * p], f1 = e[2 * p + 1];
    const unsigned h = cvt_pk_bf16(f0, f1);
    const float r0 = f0 - __uint_as_float(h << 16);
    const float r1 = f1 - __uint_as_float(h & 0xffff0000u);
    const unsigned m = cvt_pk_bf16(r0, r1);
    const float s0 = r0 - __uint_as_float(m << 16);
    const float s1 = r1 - __uint_as_float(m & 0xffff0000u);
    dl[p] = cvt_pk_bf16(s0, s1);
    dh[p] = h;
    dm[p] = m;
  }
}

// ---- prologue: W[64][2048] f32 -> ws bf16x3 in B-fragment order ----
// frag f = ksg*12 + nt*3 + sp occupies bytes [f*1024, f*1024+1024):
// lane l dwordx4 at +l*16; n = nt*16+(l&15), k = ksg*32+(l>>4)*8+{2p+h}.
__global__ __launch_bounds__(256) void w_split_kernel(
    const float* __restrict__ w, uint4* __restrict__ ws) {
  const int id = blockIdx.x * 256 + threadIdx.x;  // 16384 threads
  const int l = id & 63;
  const int nt = (id >> 6) & 3;
  const int ksg = id >> 8;  // 0..63
  const int n = nt * 16 + (l & 15);
  const int kb = ksg * 32 + ((l >> 4) << 3);
  const float* wr = w + (size_t)n * H_DIM + kb;
  const float4 a = *(const float4*)(wr);
  const float4 b = *(const float4*)(wr + 4);
  const float e[8] = {a.x, a.y, a.z, a.w, b.x, b.y, b.z, b.w};
  unsigned dh[4], dm[4], dl[4];
  split3(e, dh, dm, dl);
  const int base = (ksg * 12 + nt * 3) * 64 + l;
  ws[base] = make_uint4(dh[0], dh[1], dh[2], dh[3]);
  ws[base + 64] = make_uint4(dm[0], dm[1], dm[2], dm[3]);
  ws[base + 128] = make_uint4(dl[0], dl[1], dl[2], dl[3]);
}

// ---- main kernel ----
__global__ __launch_bounds__(512, 2) void moe_gate_kernel(
    const float* __restrict__ x, const uint4* __restrict__ wf_g,
    float* __restrict__ out, int n_tokens) {
  __shared__ char bstage[2 * 24576];     // 48 KB: B double buffer
  __shared__ float logits[N_EXP * TOK];  // 8 KB

  const int tid = threadIdx.x;
  const int l = tid & 63;
  const int w = tid >> 6;
  const int m = __builtin_amdgcn_readfirstlane(w & 1);   // token tile
  const int n4 = __builtin_amdgcn_readfirstlane(w >> 1); // expert tile
  const int t0 = blockIdx.x * TOK;

  // x A-frag address: row = t0 + m*16 + (l&15), k-base (l>>4)*8
  const float* xp =
      x + (size_t)(t0 + m * 16 + (l & 15)) * H_DIM + ((l >> 4) << 3);
  const char* wsb = (const char*)wf_g;

  // staging: wave w stages chunks 3w..3w+2 of the 24 KB iteration chunk.
  // src per-lane; dst wave-uniform (HW adds lane*16).
  auto stage = [&](int ii) {
    const char* src = wsb + (size_t)ii * 24576 + w * 3072 + l * 16;
    char* dst = bstage + (ii & 1) * 24576 + w * 3072;
#pragma unroll
    for (int j = 0; j < 3; ++j)
      __builtin_amdgcn_global_load_lds(
          (const __attribute__((address_space(1))) void*)(src + j * 1024),
          (__attribute__((address_space(3))) void*)(dst + j * 1024), 16, 0, 0);
  };

  // x loads for iteration i: frags at k = i*64 + {0,32}; float4 at +0,+4 each
  auto load_x4 = [&](float4(&dst)[4], int i) {
    const float* p = xp + i * 64;
    dst[0] = *(const float4*)(p);
    dst[1] = *(const float4*)(p + 4);
    dst[2] = *(const float4*)(p + 32);
    dst[3] = *(const float4*)(p + 36);
  };

  f32x4 acc = (f32x4){0.f, 0.f, 0.f, 0.f};
  float4 xA[4], xB[4], xC[4];

  // prologue: stage(0), then x(0), x(1); vmcnt(8) = stage(0) retired
  stage(0);
  __builtin_amdgcn_sched_barrier(0);
  load_x4(xA, 0);
  load_x4(xB, 1);
  asm volatile("s_waitcnt vmcnt(8)" ::: "memory");
  __builtin_amdgcn_s_barrier();

#pragma unroll 1
  for (int i = 0; i < NIT; ++i) {
    if (i + 1 < NIT) stage(i + 1);
    __builtin_amdgcn_sched_barrier(0);  // pin order: stage older than x
    if (i + 2 < NIT) load_x4(xC, i + 2);

    // compute from bstage[i&1], xA (loaded 2 iters ago, long retired)
    const char* lb = bstage + (i & 1) * 24576 + (n4 * 3) * 1024 + l * 16;
#pragma unroll
    for (int kk = 0; kk < 2; ++kk) {
      bf16x8 ah, am, al;
      {
        const float4 v0 = xA[kk * 2], v1 = xA[kk * 2 + 1];
        const float e[8] = {v0.x, v0.y, v0.z, v0.w, v1.x, v1.y, v1.z, v1.w};
        FragU uh, um, ul;
        split3(e, uh.u, um.u, ul.u);
        ah = uh.s;
        am = um.s;
        al = ul.s;
      }
      FragU bh, bm, bl;
      bh.q = *(const uint4*)(lb + kk * 12288 + 0);
      bm.q = *(const uint4*)(lb + kk * 12288 + 1024);
      bl.q = *(const uint4*)(lb + kk * 12288 + 2048);
      acc = __builtin_amdgcn_mfma_f32_16x16x32_bf16(ah, bh.s, acc, 0, 0, 0);
      acc = __builtin_amdgcn_mfma_f32_16x16x32_bf16(am, bh.s, acc, 0, 0, 0);
      acc = __builtin_amdgcn_mfma_f32_16x16x32_bf16(ah, bm.s, acc, 0, 0, 0);
      acc = __builtin_amdgcn_mfma_f32_16x16x32_bf16(al, bh.s, acc, 0, 0, 0);
      acc = __builtin_amdgcn_mfma_f32_16x16x32_bf16(ah, bl.s, acc, 0, 0, 0);
      acc = __builtin_amdgcn_mfma_f32_16x16x32_bf16(am, bm.s, acc, 0, 0, 0);
    }

    // rotate x prefetch (static-index moves)
#pragma unroll
    for (int j = 0; j < 4; ++j) {
      xA[j] = xB[j];
      xB[j] = xC[j];
    }

    if (i + 1 < NIT) {
      // counted wait: stage(i+1) (3 loads) is older than the 4 x(i+2) loads
      if (i + 2 < NIT)
        asm volatile("s_waitcnt vmcnt(4)" ::: "memory");
      else
        asm volatile("s_waitcnt vmcnt(0)" ::: "memory");
      __builtin_amdgcn_s_barrier();
    }
  }

  // ---- epilogue: direct C write (no k-reduce needed), top-8 ----
  __syncthreads();  // all B reads done (logits shares no space, sync for order)
  // expert e = n4*16 + (l&15); tokens m*16 + (l>>4)*4 + {0..3} (consecutive)
  *(float4*)&logits[(n4 * 16 + (l & 15)) * TOK + m * 16 + ((l >> 4) << 2)] =
      make_float4(acc[0], acc[1], acc[2], acc[3]);
  __syncthreads();

  if (tid >= TOK) return;  // 32 tokens: lanes 0..31 of wave 0

  // ---- per-lane top-8 over 64 logits (lane = token) ----
  float lg[N_EXP];
#pragma unroll
  for (int e = 0; e < N_EXP; ++e) lg[e] = logits[e * TOK + tid];

  float bw[TOPK];
  int bi[TOPK];
#pragma unroll
  for (int k = 0; k < TOPK; ++k) {
    float mx_ = lg[0];
    int mi = 0;
#pragma unroll
    for (int e = 1; e < N_EXP; ++e) {
      if (lg[e] > mx_) {  // strict > keeps lowest index on tie (lax.top_k)
        mx_ = lg[e];
        mi = e;
      }
    }
    bw[k] = mx_;
    bi[k] = mi;
#pragma unroll
    for (int e = 0; e < N_EXP; ++e)
      if (e == mi) lg[e] = -INFINITY;
  }

  // softmax over top-8 == full softmax renormalized to top-8 (exact)
  const float mx = bw[0];
  float ew[TOPK];
  float s = 0.f;
#pragma unroll
  for (int k = 0; k < TOPK; ++k) {
    ew[k] = expf(bw[k] - mx);
    s += ew[k];
  }
  const float inv = 1.f / s;

  float4 w0, w1, i0, i1;
  w0.x = ew[0] * inv; w0.y = ew[1] * inv; w0.z = ew[2] * inv; w0.w = ew[3] * inv;
  w1.x = ew[4] * inv; w1.y = ew[5] * inv; w1.z = ew[6] * inv; w1.w = ew[7] * inv;
  i0.x = (float)bi[0]; i0.y = (float)bi[1]; i0.z = (float)bi[2]; i0.w = (float)bi[3];
  i1.x = (float)bi[4]; i1.y = (float)bi[5]; i1.z = (float)bi[6]; i1.w = (float)bi[7];

  const int t = t0 + tid;
  float4* ow = reinterpret_cast<float4*>(out + (size_t)t * TOPK);
  ow[0] = w0;
  ow[1] = w1;
  float4* oi =
      reinterpret_cast<float4*>(out + (size_t)n_tokens * TOPK + (size_t)t * TOPK);
  oi[0] = i0;
  oi[1] = i1;
}

extern "C" void kernel_launch(void* const* d_in, const int* in_sizes, int n_in,
                              void* d_out, int out_size, void* d_ws,
                              size_t ws_size, hipStream_t stream) {
  const float* x = (const float*)d_in[0];
  const float* w = (const float*)d_in[1];
  float* out = (float*)d_out;
  const int n_tokens = in_sizes[0] / H_DIM;  // 16384
  // prologue: split W into B-fragment-ordered bf16x3 (768 KB in d_ws)
  w_split_kernel<<<64, 256, 0, stream>>>(w, (uint4*)d_ws);
  const int n_blocks = n_tokens / TOK;  // 512
  moe_gate_kernel<<<n_blocks, 512, 0, stream>>>(x, (const uint4*)d_ws, out,
                                                n_tokens);
}